// Round 17
// baseline (258.079 us; speedup 1.0000x reference)
//
#include <hip/hip_runtime.h>
#include <hip/hip_bf16.h>
#include <math.h>

// Problem constants (from reference)
#define NN 20000      // nodes
#define NE 320000     // edges
#define FT 8          // tokens per node
#define DM 16         // embed dim
#define FD 128        // FT*DM
#define OUTC 7        // classes
#define CHK 20        // nodes per thread in scan (1024*20 >= NN)
#define DEGB 1250     // deg blocks folded into qkv1 (NE/256)

typedef unsigned short ushort;
typedef unsigned int uint;
typedef __fp16 h2 __attribute__((ext_vector_type(2)));  // matches amdgcn builtins
union UH { uint u; h2 h; };

__device__ inline h2 u2h(uint x) { UH c; c.u = x; return c.h; }

__device__ inline float dot2(uint a, h2 b, float c) {
#if __has_builtin(__builtin_amdgcn_fdot2)
    return __builtin_amdgcn_fdot2(u2h(a), b, c, false);
#else
    h2 ah = u2h(a);
    return fmaf((float)ah.x, (float)b.x, fmaf((float)ah.y, (float)b.y, c));
#endif
}
__device__ inline float dot2u(uint a, uint b, float c) { return dot2(a, u2h(b), c); }
__device__ inline float dot2h(h2 a, h2 b, float c) {
#if __has_builtin(__builtin_amdgcn_fdot2)
    return __builtin_amdgcn_fdot2(a, b, c, false);
#else
    return fmaf((float)a.x, (float)b.x, fmaf((float)a.y, (float)b.y, c));
#endif
}

__device__ inline h2 pk(float a, float b) {
#if __has_builtin(__builtin_amdgcn_cvt_pkrtz)
    return __builtin_amdgcn_cvt_pkrtz(a, b);
#else
    h2 r; r.x = (__fp16)a; r.y = (__fp16)b; return r;
#endif
}
__device__ inline ushort f16b(float x) {
    union { __fp16 h; ushort u; } c; c.h = (__fp16)x; return c.u;
}
__device__ inline float rcpf(float x) {
#if __has_builtin(__builtin_amdgcn_rcpf)
    return __builtin_amdgcn_rcpf(x);
#else
    return 1.0f / x;
#endif
}
__device__ inline float exp2r(float x) {
#if __has_builtin(__builtin_amdgcn_exp2f)
    return __builtin_amdgcn_exp2f(x);
#else
    return exp2f(x);
#endif
}
// Fast ELU: exp(x)-1 via raw v_exp_f32 (error ~1e-7 abs, threshold 7e-2).
__device__ inline float elu_f(float x) {
    return x > 0.f ? x : exp2r(x * 1.4426950408889634f) - 1.0f;
}

// Wave-local LDS handoff (wave64 lockstep; no s_barrier needed).
__device__ inline void wave_lds_fence() { __threadfence_block(); }

#define QSCALE 0.7213475204444817f  // 0.5 * log2(e): folds score scale + exp2 domain

// ---------------------------------------------------------------------------
// kv row layout (512B, f16 indices), per head h in 0..3 a contiguous 128B:
//   K[h] at  h*64 + g*4 + dd     (g = token 0..7, dd = head-dim 0..3)
//   V[h] at  h*64 + 32 + dd*8 + g
// q stored f16, pre-scaled by QSCALE, layout [f][h][dd] (= f*16 + h*4 + dd).
// ---------------------------------------------------------------------------

// Layer-1 QKV: 2 nodes/block in parallel x 2 serial iterations.
// deg histogram folded into the first DEGB blocks.
__global__ __launch_bounds__(256) void qkv1_deg_kernel(
    const float* __restrict__ x,
    const float* __restrict__ wqkv, const float* __restrict__ bqkv,
    const int* __restrict__ dst, int* __restrict__ deg,
    ushort* __restrict__ qout, ushort* __restrict__ kvout) {
    if (blockIdx.x < DEGB) {
        const int e = blockIdx.x * 256 + threadIdx.x;
        if (e < NE) atomicAdd(&deg[dst[e]], 1);
        return;
    }
    __shared__ float sw[48 * 17];
    __shared__ float sb[48];
    __shared__ float sx[2][FD];
    __shared__ uint squ[2][64];
    __shared__ uint skvu[2][128];
    const int t = threadIdx.x;
    const int nh = t >> 7, tl = t & 127;
    const int nbase = (blockIdx.x - DEGB) * 4;
    for (int i = t; i < 48 * 16; i += 256) sw[(i >> 4) * 17 + (i & 15)] = wqkv[i];
    if (t < 48) sb[t] = bqkv[t];
    const int f = tl >> 4, d = tl & 15, h = d >> 2, dd = d & 3;
#pragma unroll
    for (int it = 0; it < 2; ++it) {
        const int n = nbase + it * 2 + nh;
        if (it) __syncthreads();
        sx[nh][tl] = x[(size_t)n * FD + tl];
        __syncthreads();
        float aq = sb[d], ak = sb[16 + d], av = sb[32 + d];
        const float* xr = &sx[nh][f * 16];
#pragma unroll
        for (int e = 0; e < 16; ++e) {
            const float xe = xr[e];
            aq = fmaf(xe, sw[d * 17 + e], aq);
            ak = fmaf(xe, sw[(16 + d) * 17 + e], ak);
            av = fmaf(xe, sw[(32 + d) * 17 + e], av);
        }
        ushort* sq = (ushort*)squ[nh];
        ushort* skv = (ushort*)skvu[nh];
        sq[tl] = f16b(aq * QSCALE);
        skv[h * 64 + f * 4 + dd] = f16b(ak);
        skv[h * 64 + 32 + dd * 8 + f] = f16b(av);
        __syncthreads();
        if (tl < 64) ((uint*)(qout + (size_t)n * FD))[tl] = squ[nh][tl];
        ((uint*)(kvout + (size_t)n * 256))[tl] = skvu[nh][tl];
    }
}

// Single-block scan, thread-serial chunks (2 syncs total).
__global__ __launch_bounds__(1024) void scan_kernel(const int* __restrict__ deg,
                                                    int* __restrict__ rowstart,
                                                    int* __restrict__ cursor) {
    __shared__ int wsum[16];
    const int t = threadIdx.x;
    const int lane = t & 63, wid = t >> 6;
    const int base = t * CHK;
    int local[CHK];
    int s = 0;
#pragma unroll
    for (int i = 0; i < CHK; ++i) {
        const int idx = base + i;
        const int d = (idx < NN) ? deg[idx] : 0;
        local[i] = s;
        s += d;
    }
    int ws = s;
    for (int off = 1; off < 64; off <<= 1) {
        int tmp = __shfl_up(ws, off);
        if (lane >= off) ws += tmp;
    }
    if (lane == 63) wsum[wid] = ws;
    __syncthreads();
    if (wid == 0) {
        int v = (lane < 16) ? wsum[lane] : 0;
        for (int off = 1; off < 16; off <<= 1) {
            int tmp = __shfl_up(v, off);
            if (lane >= off) v += tmp;
        }
        if (lane < 16) wsum[lane] = v;
    }
    __syncthreads();
    const int excl = (ws - s) + (wid > 0 ? wsum[wid - 1] : 0);
#pragma unroll
    for (int i = 0; i < CHK; ++i) {
        const int idx = base + i;
        if (idx < NN) {
            const int v = excl + local[i];
            rowstart[idx] = v;
            cursor[idx] = v;
        }
    }
    if (t == 0) rowstart[NN] = NE;
}

__global__ __launch_bounds__(256) void scatter_kernel(
    const int* __restrict__ src, const int* __restrict__ dst,
    int* __restrict__ cursor, int* __restrict__ csr_src) {
    const int e = blockIdx.x * 256 + threadIdx.x;
    if (e < NE) {
        const int pos = atomicAdd(&cursor[dst[e]], 1);
        csr_src[pos] = src[e];
    }
}

// ---------------------------------------------------------------------------
// Fused edge aggregation + node epilogue — 2 WAVES PER NODE.
// Block = 256 thr = 2 nodes x 2 waves. Wave ww of node nh owns batches
// beg + ww*16, stride 32 (16 edges each, lane=(slot,h), all 64 loads
// distinct). 40000 waves (~4.9/SIMD vs 2.4 before) and per-node critical
// path ~1.07 batches (parallel) vs 1.45 (serial). Cross-wave combine:
// partials -> LDS, one balanced __syncthreads (all working waves are
// ~1 batch long), wave 0 adds partials + runs the epilogue; wave 1 exits.
// ---------------------------------------------------------------------------
template <int PHASE>
__global__ __launch_bounds__(256) void edge_fused_kernel(
    const int* __restrict__ rowstart, const int* __restrict__ csr_src,
    const ushort* __restrict__ qh, const uint* __restrict__ kvw,
    const float* __restrict__ wo, const float* __restrict__ bo,
    const float* __restrict__ w2, const float* __restrict__ b2,  // wqkv2 | cw
    ushort* __restrict__ qout, ushort* __restrict__ kvout,        // PHASE1
    float* __restrict__ out) {                                    // PHASE2
    __shared__ float swb[1200];      // swo[0..272) sbo[272..288) then swq+sbq | scw+scb
    __shared__ float srow[2][FD];    // wave-0 partial, then combined row
    __shared__ float srow2[2][FD];   // wave-1 partial
    __shared__ uint spack[2][192];
    const int t = threadIdx.x;
    for (int i = t; i < 256; i += 256) swb[(i >> 4) * 17 + (i & 15)] = wo[i];
    if (t < 16) swb[272 + t] = bo[t];
    if (PHASE == 1) {
        for (int i = t; i < 768; i += 256) swb[288 + (i >> 4) * 17 + (i & 15)] = w2[i];
        if (t < 48) swb[1104 + t] = b2[t];
    } else {
        for (int i = t; i < OUTC * FD; i += 256) swb[288 + i] = w2[i];
        if (t < OUTC) swb[1184 + t] = b2[t];
    }
    __syncthreads();   // weights staged once per block

    const int w4 = t >> 6;
    const int nh = w4 >> 1;                  // node within block (0..1)
    const int ww = w4 & 1;                   // wave within node (0..1)
    const int n = blockIdx.x * 2 + nh;       // grid exact: NN/2
    const int lane = t & 63;
    const int slot = lane >> 2, h = lane & 3;
    const h2 one2 = {(__fp16)1.0f, (__fp16)1.0f};

    const uint* qrow = (const uint*)(qh + (size_t)n * FD);
    uint2 qp[8];
#pragma unroll
    for (int f = 0; f < 8; ++f)
        qp[f] = *(const uint2*)(qrow + f * 8 + h * 2);

    const int beg = rowstart[n], end = rowstart[n + 1];

    float acc[8][4];
#pragma unroll
    for (int f = 0; f < 8; ++f)
#pragma unroll
        for (int dd = 0; dd < 4; ++dd) acc[f][dd] = 0.f;

    const int wbeg = beg + ww * 16;          // this wave's first batch
    int e = wbeg + slot;
    uint idx = (e < end) ? (uint)csr_src[e] : 0u;
    float gate = (e < end) ? 1.0f : 0.0f;

    for (int eb = wbeg; eb < end; eb += 32) {
        const uint4* p = (const uint4*)(kvw + (size_t)idx * 128 + h * 32);
        const uint4 k0 = p[0], k1 = p[1], k2 = p[2], k3 = p[3];
        const uint4 v0 = p[4], v1 = p[5], v2 = p[6], v3 = p[7];
        const int en = eb + 32 + slot;
        const uint idxn = (en < end) ? (uint)csr_src[en] : 0u;
        const float gaten = (en < end) ? 1.0f : 0.0f;

#pragma unroll
        for (int f = 0; f < 8; ++f) {
            const uint qx = qp[f].x, qy = qp[f].y;
            float s0 = dot2u(qy, k0.y, dot2u(qx, k0.x, 0.f));
            float s1 = dot2u(qy, k0.w, dot2u(qx, k0.z, 0.f));
            float s2 = dot2u(qy, k1.y, dot2u(qx, k1.x, 0.f));
            float s3 = dot2u(qy, k1.w, dot2u(qx, k1.z, 0.f));
            float s4 = dot2u(qy, k2.y, dot2u(qx, k2.x, 0.f));
            float s5 = dot2u(qy, k2.w, dot2u(qx, k2.z, 0.f));
            float s6 = dot2u(qy, k3.y, dot2u(qx, k3.x, 0.f));
            float s7 = dot2u(qy, k3.w, dot2u(qx, k3.z, 0.f));
            s0 = exp2r(s0); s1 = exp2r(s1); s2 = exp2r(s2); s3 = exp2r(s3);
            s4 = exp2r(s4); s5 = exp2r(s5); s6 = exp2r(s6); s7 = exp2r(s7);
            const h2 e0 = pk(s0, s1), e1 = pk(s2, s3), e2 = pk(s4, s5), e3 = pk(s6, s7);
            const float sum =
                dot2h(e3, one2, dot2h(e2, one2, dot2h(e1, one2, dot2h(e0, one2, 0.f))));
            const float inv = gate * rcpf(sum);
            const float p0 = dot2(v0.w, e3, dot2(v0.z, e2, dot2(v0.y, e1, dot2(v0.x, e0, 0.f))));
            const float p1 = dot2(v1.w, e3, dot2(v1.z, e2, dot2(v1.y, e1, dot2(v1.x, e0, 0.f))));
            const float p2 = dot2(v2.w, e3, dot2(v2.z, e2, dot2(v2.y, e1, dot2(v2.x, e0, 0.f))));
            const float p3 = dot2(v3.w, e3, dot2(v3.z, e2, dot2(v3.y, e1, dot2(v3.x, e0, 0.f))));
            acc[f][0] = fmaf(p0, inv, acc[f][0]);
            acc[f][1] = fmaf(p1, inv, acc[f][1]);
            acc[f][2] = fmaf(p2, inv, acc[f][2]);
            acc[f][3] = fmaf(p3, inv, acc[f][3]);
        }
        idx = idxn; gate = gaten;
    }

#pragma unroll
    for (int f = 0; f < 8; ++f)
#pragma unroll
        for (int dd = 0; dd < 4; ++dd) {
            float a = acc[f][dd];
            a += __shfl_xor(a, 4);
            a += __shfl_xor(a, 8);
            a += __shfl_xor(a, 16);
            a += __shfl_xor(a, 32);
            acc[f][dd] = a;
        }
    if (slot == 0) {
        float* dstrow = (ww == 0) ? srow[nh] : srow2[nh];
#pragma unroll
        for (int f = 0; f < 8; ++f)
            *(float4*)(&dstrow[f * 16 + h * 4]) =
                make_float4(acc[f][0], acc[f][1], acc[f][2], acc[f][3]);
    }
    __syncthreads();    // balanced: all working waves ~1 batch long
    if (ww == 1) return;  // no further barriers below — legal early exit

    // combine the two wave partials (64 lanes x 2 floats)
    srow[nh][lane] += srow2[nh][lane];
    srow[nh][lane + 64] += srow2[nh][lane + 64];
    wave_lds_fence();

    const int dgr = end - beg;
    const int f0 = lane >> 4, d = lane & 15;
    const float* swo = swb;
    const float* sbo = swb + 272;
    float hv0 = (float)dgr * sbo[d];
    float hv1 = hv0;
#pragma unroll
    for (int ee = 0; ee < 16; ++ee) {
        const float wde = swo[d * 17 + ee];
        hv0 = fmaf(srow[nh][f0 * 16 + ee], wde, hv0);
        hv1 = fmaf(srow[nh][(f0 + 4) * 16 + ee], wde, hv1);
    }
    hv0 = elu_f(hv0);
    hv1 = elu_f(hv1);

    if (PHASE == 1) {
        srow[nh][lane] = hv0;
        srow[nh][lane + 64] = hv1;
        wave_lds_fence();
        const float* swq = swb + 288;
        const float* sbq = swb + 1104;
        float aq0 = sbq[d], ak0 = sbq[16 + d], av0 = sbq[32 + d];
        float aq1 = aq0, ak1 = ak0, av1 = av0;
#pragma unroll
        for (int ee = 0; ee < 16; ++ee) {
            const float x0 = srow[nh][f0 * 16 + ee];
            const float x1 = srow[nh][(f0 + 4) * 16 + ee];
            const float wq = swq[d * 17 + ee];
            const float wk = swq[(16 + d) * 17 + ee];
            const float wvw = swq[(32 + d) * 17 + ee];
            aq0 = fmaf(x0, wq, aq0); aq1 = fmaf(x1, wq, aq1);
            ak0 = fmaf(x0, wk, ak0); ak1 = fmaf(x1, wk, ak1);
            av0 = fmaf(x0, wvw, av0); av1 = fmaf(x1, wvw, av1);
        }
        ushort* sq = (ushort*)&spack[nh][0];
        ushort* skv = (ushort*)&spack[nh][64];
        const int hh = d >> 2, dd = d & 3;
        sq[lane] = f16b(aq0 * QSCALE);
        sq[lane + 64] = f16b(aq1 * QSCALE);
        skv[hh * 64 + f0 * 4 + dd] = f16b(ak0);
        skv[hh * 64 + (f0 + 4) * 4 + dd] = f16b(ak1);
        skv[hh * 64 + 32 + dd * 8 + f0] = f16b(av0);
        skv[hh * 64 + 32 + dd * 8 + f0 + 4] = f16b(av1);
        wave_lds_fence();
        ((uint*)(qout + (size_t)n * FD))[lane] = spack[nh][lane];
        uint* kvo = (uint*)(kvout + (size_t)n * 256);
        kvo[lane] = spack[nh][64 + lane];
        kvo[lane + 64] = spack[nh][128 + lane];
    } else {
        const float* scw = swb + 288;
        const float* scb = swb + 1184;
        float p[OUTC];
#pragma unroll
        for (int c = 0; c < OUTC; ++c)
            p[c] = fmaf(hv0, scw[c * FD + lane], hv1 * scw[c * FD + lane + 64]);
#pragma unroll
        for (int c = 0; c < OUTC; ++c)
            for (int off = 32; off; off >>= 1) p[c] += __shfl_xor(p[c], off);
        if (lane == 0) {
            float lg[OUTC];
            float m = -1e30f;
#pragma unroll
            for (int c = 0; c < OUTC; ++c) { lg[c] = p[c] + scb[c]; m = fmaxf(m, lg[c]); }
            float s = 0.f;
#pragma unroll
            for (int c = 0; c < OUTC; ++c) s += __expf(lg[c] - m);
            const float lse = m + logf(s);
#pragma unroll
            for (int c = 0; c < OUTC; ++c) out[(size_t)n * OUTC + c] = lg[c] - lse;
        }
    }
}

extern "C" void kernel_launch(void* const* d_in, const int* in_sizes, int n_in,
                              void* d_out, int out_size, void* d_ws, size_t ws_size,
                              hipStream_t stream) {
    const float* x      = (const float*)d_in[0];
    const int*   ei     = (const int*)d_in[1];
    const float* w1qkv  = (const float*)d_in[2];
    const float* b1qkv  = (const float*)d_in[3];
    const float* w1o    = (const float*)d_in[4];
    const float* b1o    = (const float*)d_in[5];
    const float* w2qkv  = (const float*)d_in[6];
    const float* b2qkv  = (const float*)d_in[7];
    const float* w2o    = (const float*)d_in[8];
    const float* b2o    = (const float*)d_in[9];
    const float* outw   = (const float*)d_in[10];
    const float* outb   = (const float*)d_in[11];
    float* out = (float*)d_out;

    const int* srcp = ei;        // edge_index[0]
    const int* dstp = ei + NE;   // edge_index[1]

    ushort* qh    = (ushort*)d_ws;
    ushort* kvh   = qh + (size_t)NN * FD;
    ushort* qh2   = kvh + (size_t)NN * 256;
    ushort* kvh2  = qh2 + (size_t)NN * FD;
    int*    deg      = (int*)(kvh2 + (size_t)NN * 256);
    int*    rowstart = deg + NN;          // NN+1 entries
    int*    cursor   = rowstart + NN + 1;
    int*    csr_src  = cursor + NN;       // NE

    (void)hipMemsetAsync(deg, 0, NN * sizeof(int), stream);
    qkv1_deg_kernel<<<DEGB + NN / 4, 256, 0, stream>>>(x, w1qkv, b1qkv, dstp, deg, qh, kvh);
    scan_kernel<<<1, 1024, 0, stream>>>(deg, rowstart, cursor);
    scatter_kernel<<<(NE + 255) / 256, 256, 0, stream>>>(srcp, dstp, cursor, csr_src);

    edge_fused_kernel<1><<<NN / 2, 256, 0, stream>>>(
        rowstart, csr_src, qh, (const uint*)kvh, w1o, b1o, w2qkv, b2qkv,
        qh2, kvh2, nullptr);
    edge_fused_kernel<2><<<NN / 2, 256, 0, stream>>>(
        rowstart, csr_src, qh2, (const uint*)kvh2, w2o, b2o, outw, outb,
        nullptr, nullptr, out);
}

// Round 18
// 204.802 us; speedup vs baseline: 1.2601x; 1.2601x over previous
//
#include <hip/hip_runtime.h>
#include <hip/hip_bf16.h>
#include <math.h>

// Problem constants (from reference)
#define NN 20000      // nodes
#define NE 320000     // edges
#define FT 8          // tokens per node
#define DM 16         // embed dim
#define FD 128        // FT*DM
#define OUTC 7        // classes
#define CHK 20        // nodes per thread in scan (1024*20 >= NN)
#define DEGB 1250     // deg blocks folded into qkv1 (NE/256)

typedef unsigned short ushort;
typedef unsigned int uint;
typedef __fp16 h2 __attribute__((ext_vector_type(2)));  // matches amdgcn builtins
union UH { uint u; h2 h; };

__device__ inline h2 u2h(uint x) { UH c; c.u = x; return c.h; }

__device__ inline float dot2(uint a, h2 b, float c) {
#if __has_builtin(__builtin_amdgcn_fdot2)
    return __builtin_amdgcn_fdot2(u2h(a), b, c, false);
#else
    h2 ah = u2h(a);
    return fmaf((float)ah.x, (float)b.x, fmaf((float)ah.y, (float)b.y, c));
#endif
}
__device__ inline float dot2u(uint a, uint b, float c) { return dot2(a, u2h(b), c); }
__device__ inline float dot2h(h2 a, h2 b, float c) {
#if __has_builtin(__builtin_amdgcn_fdot2)
    return __builtin_amdgcn_fdot2(a, b, c, false);
#else
    return fmaf((float)a.x, (float)b.x, fmaf((float)a.y, (float)b.y, c));
#endif
}

__device__ inline h2 pk(float a, float b) {
#if __has_builtin(__builtin_amdgcn_cvt_pkrtz)
    return __builtin_amdgcn_cvt_pkrtz(a, b);
#else
    h2 r; r.x = (__fp16)a; r.y = (__fp16)b; return r;
#endif
}
__device__ inline ushort f16b(float x) {
    union { __fp16 h; ushort u; } c; c.h = (__fp16)x; return c.u;
}
__device__ inline float rcpf(float x) {
#if __has_builtin(__builtin_amdgcn_rcpf)
    return __builtin_amdgcn_rcpf(x);
#else
    return 1.0f / x;
#endif
}
__device__ inline float exp2r(float x) {
#if __has_builtin(__builtin_amdgcn_exp2f)
    return __builtin_amdgcn_exp2f(x);
#else
    return exp2f(x);
#endif
}
// Fast ELU: exp(x)-1 via raw v_exp_f32 (error ~1e-7 abs, threshold 7e-2).
__device__ inline float elu_f(float x) {
    return x > 0.f ? x : exp2r(x * 1.4426950408889634f) - 1.0f;
}

// Wave-local LDS handoff (wave64 lockstep; no s_barrier needed).
__device__ inline void wave_lds_fence() { __threadfence_block(); }

#define QSCALE 0.7213475204444817f  // 0.5 * log2(e): folds score scale + exp2 domain

// ---------------------------------------------------------------------------
// kv row layout (512B, f16 indices), per head h in 0..3 a contiguous 128B:
//   K[h] at  h*64 + g*4 + dd     (g = token 0..7, dd = head-dim 0..3)
//   V[h] at  h*64 + 32 + dd*8 + g
// q stored f16, pre-scaled by QSCALE, layout [f][h][dd] (= f*16 + h*4 + dd).
// ---------------------------------------------------------------------------

// Layer-1 QKV: 2 nodes/block in parallel x 2 serial iterations (weights
// staged once per block, amortized over 4 nodes). deg histogram folded
// into the first DEGB blocks.
__global__ __launch_bounds__(256) void qkv1_deg_kernel(
    const float* __restrict__ x,
    const float* __restrict__ wqkv, const float* __restrict__ bqkv,
    const int* __restrict__ dst, int* __restrict__ deg,
    ushort* __restrict__ qout, ushort* __restrict__ kvout) {
    if (blockIdx.x < DEGB) {
        const int e = blockIdx.x * 256 + threadIdx.x;
        if (e < NE) atomicAdd(&deg[dst[e]], 1);
        return;
    }
    __shared__ float sw[48 * 17];
    __shared__ float sb[48];
    __shared__ float sx[2][FD];
    __shared__ uint squ[2][64];
    __shared__ uint skvu[2][128];
    const int t = threadIdx.x;
    const int nh = t >> 7, tl = t & 127;
    const int nbase = (blockIdx.x - DEGB) * 4;
    for (int i = t; i < 48 * 16; i += 256) sw[(i >> 4) * 17 + (i & 15)] = wqkv[i];
    if (t < 48) sb[t] = bqkv[t];
    const int f = tl >> 4, d = tl & 15, h = d >> 2, dd = d & 3;
#pragma unroll
    for (int it = 0; it < 2; ++it) {
        const int n = nbase + it * 2 + nh;
        if (it) __syncthreads();          // protect sx/squ reuse
        sx[nh][tl] = x[(size_t)n * FD + tl];
        __syncthreads();                   // sx (+ weights on it==0) ready
        float aq = sb[d], ak = sb[16 + d], av = sb[32 + d];
        const float* xr = &sx[nh][f * 16];
#pragma unroll
        for (int e = 0; e < 16; ++e) {
            const float xe = xr[e];
            aq = fmaf(xe, sw[d * 17 + e], aq);
            ak = fmaf(xe, sw[(16 + d) * 17 + e], ak);
            av = fmaf(xe, sw[(32 + d) * 17 + e], av);
        }
        ushort* sq = (ushort*)squ[nh];
        ushort* skv = (ushort*)skvu[nh];
        sq[tl] = f16b(aq * QSCALE);
        skv[h * 64 + f * 4 + dd] = f16b(ak);
        skv[h * 64 + 32 + dd * 8 + f] = f16b(av);
        __syncthreads();
        if (tl < 64) ((uint*)(qout + (size_t)n * FD))[tl] = squ[nh][tl];
        ((uint*)(kvout + (size_t)n * 256))[tl] = skvu[nh][tl];
    }
}

// Single-block scan, thread-serial chunks (2 syncs total).
__global__ __launch_bounds__(1024) void scan_kernel(const int* __restrict__ deg,
                                                    int* __restrict__ rowstart,
                                                    int* __restrict__ cursor) {
    __shared__ int wsum[16];
    const int t = threadIdx.x;
    const int lane = t & 63, wid = t >> 6;
    const int base = t * CHK;
    int local[CHK];
    int s = 0;
#pragma unroll
    for (int i = 0; i < CHK; ++i) {
        const int idx = base + i;
        const int d = (idx < NN) ? deg[idx] : 0;
        local[i] = s;
        s += d;
    }
    int ws = s;
    for (int off = 1; off < 64; off <<= 1) {
        int tmp = __shfl_up(ws, off);
        if (lane >= off) ws += tmp;
    }
    if (lane == 63) wsum[wid] = ws;
    __syncthreads();
    if (wid == 0) {
        int v = (lane < 16) ? wsum[lane] : 0;
        for (int off = 1; off < 16; off <<= 1) {
            int tmp = __shfl_up(v, off);
            if (lane >= off) v += tmp;
        }
        if (lane < 16) wsum[lane] = v;
    }
    __syncthreads();
    const int excl = (ws - s) + (wid > 0 ? wsum[wid - 1] : 0);
#pragma unroll
    for (int i = 0; i < CHK; ++i) {
        const int idx = base + i;
        if (idx < NN) {
            const int v = excl + local[i];
            rowstart[idx] = v;
            cursor[idx] = v;
        }
    }
    if (t == 0) rowstart[NN] = NE;
}

__global__ __launch_bounds__(256) void scatter_kernel(
    const int* __restrict__ src, const int* __restrict__ dst,
    int* __restrict__ cursor, int* __restrict__ csr_src) {
    const int e = blockIdx.x * 256 + threadIdx.x;
    if (e < NE) {
        const int pos = atomicAdd(&cursor[dst[e]], 1);
        csr_src[pos] = src[e];
    }
}

// ---------------------------------------------------------------------------
// Fused edge aggregation + node epilogue (R16 best configuration).
// Main loop: 16 edges/wave-batch, lane=(slot,h), all 64 loads distinct;
// softmax sum via packed fdot2 on the already-pk'd f16 exps. Epilogue uses
// fast ELU; wave-local fences only (one wave per node, no cross-wave
// rendezvous — R15/R17 showed barriers on this kernel cost, never pay).
// ---------------------------------------------------------------------------
template <int PHASE>
__global__ __launch_bounds__(256) void edge_fused_kernel(
    const int* __restrict__ rowstart, const int* __restrict__ csr_src,
    const ushort* __restrict__ qh, const uint* __restrict__ kvw,
    const float* __restrict__ wo, const float* __restrict__ bo,
    const float* __restrict__ w2, const float* __restrict__ b2,  // wqkv2 | cw
    ushort* __restrict__ qout, ushort* __restrict__ kvout,        // PHASE1
    float* __restrict__ out) {                                    // PHASE2
    __shared__ float swb[1200];      // swo[0..272) sbo[272..288) then swq+sbq | scw+scb
    __shared__ float srow[4][FD];
    __shared__ uint spack[4][192];
    const int t = threadIdx.x;
    for (int i = t; i < 256; i += 256) swb[(i >> 4) * 17 + (i & 15)] = wo[i];
    if (t < 16) swb[272 + t] = bo[t];
    if (PHASE == 1) {
        for (int i = t; i < 768; i += 256) swb[288 + (i >> 4) * 17 + (i & 15)] = w2[i];
        if (t < 48) swb[1104 + t] = b2[t];
    } else {
        for (int i = t; i < OUTC * FD; i += 256) swb[288 + i] = w2[i];
        if (t < OUTC) swb[1184 + t] = b2[t];
    }
    __syncthreads();   // cross-wave: weights staged once per block

    const int wv = t >> 6;
    const int n = blockIdx.x * 4 + wv;       // grid exact: NN/4
    const int lane = t & 63;
    const int slot = lane >> 2, h = lane & 3;
    const h2 one2 = {(__fp16)1.0f, (__fp16)1.0f};

    const uint* qrow = (const uint*)(qh + (size_t)n * FD);
    uint2 qp[8];
#pragma unroll
    for (int f = 0; f < 8; ++f)
        qp[f] = *(const uint2*)(qrow + f * 8 + h * 2);

    const int beg = rowstart[n], end = rowstart[n + 1];

    float acc[8][4];
#pragma unroll
    for (int f = 0; f < 8; ++f)
#pragma unroll
        for (int dd = 0; dd < 4; ++dd) acc[f][dd] = 0.f;

    int e = beg + slot;
    uint idx = (e < end) ? (uint)csr_src[e] : 0u;
    float gate = (e < end) ? 1.0f : 0.0f;

    for (int eb = beg; eb < end; eb += 16) {
        const uint4* p = (const uint4*)(kvw + (size_t)idx * 128 + h * 32);
        const uint4 k0 = p[0], k1 = p[1], k2 = p[2], k3 = p[3];
        const uint4 v0 = p[4], v1 = p[5], v2 = p[6], v3 = p[7];
        const int en = eb + 16 + slot;
        const uint idxn = (en < end) ? (uint)csr_src[en] : 0u;
        const float gaten = (en < end) ? 1.0f : 0.0f;

#pragma unroll
        for (int f = 0; f < 8; ++f) {
            const uint qx = qp[f].x, qy = qp[f].y;
            float s0 = dot2u(qy, k0.y, dot2u(qx, k0.x, 0.f));
            float s1 = dot2u(qy, k0.w, dot2u(qx, k0.z, 0.f));
            float s2 = dot2u(qy, k1.y, dot2u(qx, k1.x, 0.f));
            float s3 = dot2u(qy, k1.w, dot2u(qx, k1.z, 0.f));
            float s4 = dot2u(qy, k2.y, dot2u(qx, k2.x, 0.f));
            float s5 = dot2u(qy, k2.w, dot2u(qx, k2.z, 0.f));
            float s6 = dot2u(qy, k3.y, dot2u(qx, k3.x, 0.f));
            float s7 = dot2u(qy, k3.w, dot2u(qx, k3.z, 0.f));
            s0 = exp2r(s0); s1 = exp2r(s1); s2 = exp2r(s2); s3 = exp2r(s3);
            s4 = exp2r(s4); s5 = exp2r(s5); s6 = exp2r(s6); s7 = exp2r(s7);
            const h2 e0 = pk(s0, s1), e1 = pk(s2, s3), e2 = pk(s4, s5), e3 = pk(s6, s7);
            const float sum =
                dot2h(e3, one2, dot2h(e2, one2, dot2h(e1, one2, dot2h(e0, one2, 0.f))));
            const float inv = gate * rcpf(sum);
            const float p0 = dot2(v0.w, e3, dot2(v0.z, e2, dot2(v0.y, e1, dot2(v0.x, e0, 0.f))));
            const float p1 = dot2(v1.w, e3, dot2(v1.z, e2, dot2(v1.y, e1, dot2(v1.x, e0, 0.f))));
            const float p2 = dot2(v2.w, e3, dot2(v2.z, e2, dot2(v2.y, e1, dot2(v2.x, e0, 0.f))));
            const float p3 = dot2(v3.w, e3, dot2(v3.z, e2, dot2(v3.y, e1, dot2(v3.x, e0, 0.f))));
            acc[f][0] = fmaf(p0, inv, acc[f][0]);
            acc[f][1] = fmaf(p1, inv, acc[f][1]);
            acc[f][2] = fmaf(p2, inv, acc[f][2]);
            acc[f][3] = fmaf(p3, inv, acc[f][3]);
        }
        idx = idxn; gate = gaten;
    }

#pragma unroll
    for (int f = 0; f < 8; ++f)
#pragma unroll
        for (int dd = 0; dd < 4; ++dd) {
            float a = acc[f][dd];
            a += __shfl_xor(a, 4);
            a += __shfl_xor(a, 8);
            a += __shfl_xor(a, 16);
            a += __shfl_xor(a, 32);
            acc[f][dd] = a;
        }
    if (slot == 0) {
#pragma unroll
        for (int f = 0; f < 8; ++f)
            *(float4*)(&srow[wv][f * 16 + h * 4]) =
                make_float4(acc[f][0], acc[f][1], acc[f][2], acc[f][3]);
    }
    wave_lds_fence();   // same-wave handoff (writers: slot==0 lanes)

    const int dgr = end - beg;
    const int f0 = lane >> 4, d = lane & 15;
    const float* swo = swb;
    const float* sbo = swb + 272;
    float hv0 = (float)dgr * sbo[d];
    float hv1 = hv0;
#pragma unroll
    for (int ee = 0; ee < 16; ++ee) {
        const float wde = swo[d * 17 + ee];
        hv0 = fmaf(srow[wv][f0 * 16 + ee], wde, hv0);
        hv1 = fmaf(srow[wv][(f0 + 4) * 16 + ee], wde, hv1);
    }
    hv0 = elu_f(hv0);
    hv1 = elu_f(hv1);

    if (PHASE == 1) {
        srow[wv][lane] = hv0;
        srow[wv][lane + 64] = hv1;
        wave_lds_fence();
        const float* swq = swb + 288;
        const float* sbq = swb + 1104;
        float aq0 = sbq[d], ak0 = sbq[16 + d], av0 = sbq[32 + d];
        float aq1 = aq0, ak1 = ak0, av1 = av0;
#pragma unroll
        for (int ee = 0; ee < 16; ++ee) {
            const float x0 = srow[wv][f0 * 16 + ee];
            const float x1 = srow[wv][(f0 + 4) * 16 + ee];
            const float wq = swq[d * 17 + ee];
            const float wk = swq[(16 + d) * 17 + ee];
            const float wvw = swq[(32 + d) * 17 + ee];
            aq0 = fmaf(x0, wq, aq0); aq1 = fmaf(x1, wq, aq1);
            ak0 = fmaf(x0, wk, ak0); ak1 = fmaf(x1, wk, ak1);
            av0 = fmaf(x0, wvw, av0); av1 = fmaf(x1, wvw, av1);
        }
        ushort* sq = (ushort*)&spack[wv][0];
        ushort* skv = (ushort*)&spack[wv][64];
        const int hh = d >> 2, dd = d & 3;
        sq[lane] = f16b(aq0 * QSCALE);
        sq[lane + 64] = f16b(aq1 * QSCALE);
        skv[hh * 64 + f0 * 4 + dd] = f16b(ak0);
        skv[hh * 64 + (f0 + 4) * 4 + dd] = f16b(ak1);
        skv[hh * 64 + 32 + dd * 8 + f0] = f16b(av0);
        skv[hh * 64 + 32 + dd * 8 + f0 + 4] = f16b(av1);
        wave_lds_fence();
        ((uint*)(qout + (size_t)n * FD))[lane] = spack[wv][lane];
        uint* kvo = (uint*)(kvout + (size_t)n * 256);
        kvo[lane] = spack[wv][64 + lane];
        kvo[lane + 64] = spack[wv][128 + lane];
    } else {
        const float* scw = swb + 288;
        const float* scb = swb + 1184;
        float p[OUTC];
#pragma unroll
        for (int c = 0; c < OUTC; ++c)
            p[c] = fmaf(hv0, scw[c * FD + lane], hv1 * scw[c * FD + lane + 64]);
#pragma unroll
        for (int c = 0; c < OUTC; ++c)
            for (int off = 32; off; off >>= 1) p[c] += __shfl_xor(p[c], off);
        if (lane == 0) {
            float lg[OUTC];
            float m = -1e30f;
#pragma unroll
            for (int c = 0; c < OUTC; ++c) { lg[c] = p[c] + scb[c]; m = fmaxf(m, lg[c]); }
            float s = 0.f;
#pragma unroll
            for (int c = 0; c < OUTC; ++c) s += __expf(lg[c] - m);
            const float lse = m + logf(s);
#pragma unroll
            for (int c = 0; c < OUTC; ++c) out[(size_t)n * OUTC + c] = lg[c] - lse;
        }
    }
}

extern "C" void kernel_launch(void* const* d_in, const int* in_sizes, int n_in,
                              void* d_out, int out_size, void* d_ws, size_t ws_size,
                              hipStream_t stream) {
    const float* x      = (const float*)d_in[0];
    const int*   ei     = (const int*)d_in[1];
    const float* w1qkv  = (const float*)d_in[2];
    const float* b1qkv  = (const float*)d_in[3];
    const float* w1o    = (const float*)d_in[4];
    const float* b1o    = (const float*)d_in[5];
    const float* w2qkv  = (const float*)d_in[6];
    const float* b2qkv  = (const float*)d_in[7];
    const float* w2o    = (const float*)d_in[8];
    const float* b2o    = (const float*)d_in[9];
    const float* outw   = (const float*)d_in[10];
    const float* outb   = (const float*)d_in[11];
    float* out = (float*)d_out;

    const int* srcp = ei;        // edge_index[0]
    const int* dstp = ei + NE;   // edge_index[1]

    ushort* qh    = (ushort*)d_ws;
    ushort* kvh   = qh + (size_t)NN * FD;
    ushort* qh2   = kvh + (size_t)NN * 256;
    ushort* kvh2  = qh2 + (size_t)NN * FD;
    int*    deg      = (int*)(kvh2 + (size_t)NN * 256);
    int*    rowstart = deg + NN;          // NN+1 entries
    int*    cursor   = rowstart + NN + 1;
    int*    csr_src  = cursor + NN;       // NE

    (void)hipMemsetAsync(deg, 0, NN * sizeof(int), stream);
    qkv1_deg_kernel<<<DEGB + NN / 4, 256, 0, stream>>>(x, w1qkv, b1qkv, dstp, deg, qh, kvh);
    scan_kernel<<<1, 1024, 0, stream>>>(deg, rowstart, cursor);
    scatter_kernel<<<(NE + 255) / 256, 256, 0, stream>>>(srcp, dstp, cursor, csr_src);

    edge_fused_kernel<1><<<NN / 4, 256, 0, stream>>>(
        rowstart, csr_src, qh, (const uint*)kvh, w1o, b1o, w2qkv, b2qkv,
        qh2, kvh2, nullptr);
    edge_fused_kernel<2><<<NN / 4, 256, 0, stream>>>(
        rowstart, csr_src, qh2, (const uint*)kvh2, w2o, b2o, outw, outb,
        nullptr, nullptr, out);
}